// Round 13
// baseline (44.456 us; speedup 1.0000x reference)
//
#include <hip/hip_runtime.h>
#include <cstddef>

constexpr int NGF    = 80;
constexpr int TLEN   = 1000;
constexpr int SPLICE = 10;
constexpr int PATCH  = 2 * SPLICE + 1;  // 21
constexpr int NH     = 50;
constexpr int FB     = 16;              // f per block
constexpr int TC     = 40;              // t per block
constexpr int SW     = 74;              // even (float2 reads); 74%32=10 spreads banks
constexpr float NL2E = -1.44269504088896341f;

typedef __attribute__((ext_vector_type(8))) short  short8;
typedef __attribute__((ext_vector_type(4))) float  f32x4;
typedef __attribute__((ext_vector_type(2))) float  f32x2;

__device__ __forceinline__ unsigned short f32_to_bf16(float f) {
    unsigned int u = __builtin_bit_cast(unsigned int, f);
    u += 0x7fffu + ((u >> 16) & 1u);   // RNE
    return (unsigned short)(u >> 16);
}

#define SIG(s)  __builtin_amdgcn_rcpf(1.0f + __builtin_amdgcn_exp2f(s))
#define EXP2(s) __builtin_amdgcn_exp2f(s)
#define RCP(s)  __builtin_amdgcn_rcpf(s)
#define FMA2(a, b, c) __builtin_elementwise_fma((a), (b), (c))

__global__ __launch_bounds__(256, 4) void relevance_mfma(
    const float* __restrict__ x,    // [B, NGF, TLEN]
    const float* __restrict__ W1,   // [NH, PATCH]
    const float* __restrict__ b1,   // [NH]
    const float* __restrict__ W2,   // [NH]
    const float* __restrict__ b2,   // [1]
    float* __restrict__ out)        // [B, TLEN, NGF]
{
    const int tid  = threadIdx.x;
    const int wave = tid >> 6;
    const int lane = tid & 63;
    const int q    = lane >> 4;
    const int jj   = lane & 15;
    const unsigned bx = blockIdx.x;
    const int fc   = bx % 5u;           // f-chunk
    const int tc   = bx / 5u;           // t-chunk
    const int f0   = fc * FB;
    const int t0   = tc * TC;
    const int b    = blockIdx.y;

    __shared__ float  seg[FB * SW];     // seg[fl][c] = xpad[b][f0+fl][t0+c]
    __shared__ uint4  frg[4][64];       // W1 fragments, built once per block
    __shared__ float4 w2s[4][64];       // per-lane W2 quads, built once per block

    // ---- stage x region (zero-padded)
    const float* xb = x + ((size_t)b * NGF + f0) * TLEN;
    for (int i = tid; i < FB * SW; i += 256) {
        const unsigned fl = (unsigned)i / SW;
        const int c = i - (int)fl * SW;
        const int gx = t0 + c - SPLICE;
        seg[i] = (gx >= 0 && gx < TLEN) ? xb[fl * TLEN + gx] : 0.0f;
    }

    // ---- fragment build, deduplicated: wave n builds fragment-set n only.
    // A = W1 (M = j). A[m=jj][k=8q+e], pre-scaled by -log2(e), b1 in k=21.
    {
        const int j = 16 * wave + jj;
        unsigned int us[8];
        #pragma unroll
        for (int e = 0; e < 8; ++e) {
            const int k = 8 * q + e;
            float v = 0.0f;
            if (j < NH) {
                if (k < PATCH)       v = NL2E * W1[j * PATCH + k];
                else if (k == PATCH) v = NL2E * b1[j];
            }
            us[e] = f32_to_bf16(v);
        }
        uint4 u;
        u.x = us[0] | (us[1] << 16);
        u.y = us[2] | (us[3] << 16);
        u.z = us[4] | (us[5] << 16);
        u.w = us[6] | (us[7] << 16);
        frg[wave][lane] = u;

        const int jw = 16 * wave + 4 * q;
        float4 wv;
        wv.x = (jw + 0 < NH) ? NL2E * W2[jw + 0] : 0.0f;
        wv.y = (jw + 1 < NH) ? NL2E * W2[jw + 1] : 0.0f;
        wv.z = (jw + 2 < NH) ? NL2E * W2[jw + 2] : 0.0f;
        wv.w = (jw + 3 < NH) ? NL2E * W2[jw + 3] : 0.0f;
        w2s[wave][lane] = wv;
    }

    __syncthreads();

    // ---- every wave reads the shared fragments back
    union FragU { uint4 u4; short8 s8; };
    FragU w1f0, w1f1, w1f2, w1f3;
    w1f0.u4 = frg[0][lane];
    w1f1.u4 = frg[1][lane];
    w1f2.u4 = frg[2][lane];
    w1f3.u4 = frg[3][lane];

    // packed W2, duplicated across the f32x2 lanes: each QUADPK call pairs the
    // SAME j-quad of tile0 (x) and tile1 (y), so weights are {w, w}.
    f32x2 wa0, wa1, wa2, wa3;   // acc-set 0 (j = 0 + 4q + r)
    f32x2 wb0, wb1, wb2, wb3;   // acc-set 1 (j = 16 + 4q + r)
    f32x2 wc0, wc1, wc2, wc3;   // acc-set 2 (j = 32 + 4q + r)
    f32x2 wd0, wd1;             // acc-set 3 pair (j = 48, 49)
    {
        const float4 t0v = w2s[0][lane], t1v = w2s[1][lane];
        const float4 t2v = w2s[2][lane], t3v = w2s[3][lane];
        wa0 = (f32x2){t0v.x, t0v.x}; wa1 = (f32x2){t0v.y, t0v.y};
        wa2 = (f32x2){t0v.z, t0v.z}; wa3 = (f32x2){t0v.w, t0v.w};
        wb0 = (f32x2){t1v.x, t1v.x}; wb1 = (f32x2){t1v.y, t1v.y};
        wb2 = (f32x2){t1v.z, t1v.z}; wb3 = (f32x2){t1v.w, t1v.w};
        wc0 = (f32x2){t2v.x, t2v.x}; wc1 = (f32x2){t2v.y, t2v.y};
        wc2 = (f32x2){t2v.z, t2v.z}; wc3 = (f32x2){t2v.w, t2v.w};
        wd0 = (f32x2){t3v.x, t3v.x}; wd1 = (f32x2){t3v.y, t3v.y};
    }
    const float nb2 = NL2E * b2[0];

    // bias-slot patch masks (k=21 lives in q==2's dword 2 hi half)
    const int selA = (q == 2) ? 0x0000FFFF : ~0;
    const int selB = (q == 2) ? 0x3F800000 : 0;

    // dual quad-rational: ACCA feeds ZV.x (tile0), ACCB feeds ZV.y (tile1)
#define QUADPK(ACCA, ACCB, W0, W1_, W2_, W3_, ZV)                            \
        {                                                                    \
            const f32x2 u0 = {EXP2(ACCA[0]), EXP2(ACCB[0])};                 \
            const f32x2 u1 = {EXP2(ACCA[1]), EXP2(ACCB[1])};                 \
            const f32x2 u2 = {EXP2(ACCA[2]), EXP2(ACCB[2])};                 \
            const f32x2 u3 = {EXP2(ACCA[3]), EXP2(ACCB[3])};                 \
            const f32x2 n01 = FMA2(W0, u1, FMA2(W1_, u0, W0 + W1_));         \
            const f32x2 n23 = FMA2(W2_, u3, FMA2(W3_, u2, W2_ + W3_));       \
            const f32x2 d01 = FMA2(u0, u1, u0 + u1) + (f32x2){1.0f, 1.0f};   \
            const f32x2 d23 = FMA2(u2, u3, u2 + u3) + (f32x2){1.0f, 1.0f};   \
            const f32x2 nq  = FMA2(n01, d23, n23 * d01);                     \
            const f32x2 dq  = d01 * d23;                                     \
            ZV.x = fmaf(nq.x, RCP(dq.x), ZV.x);                              \
            ZV.y = fmaf(nq.y, RCP(dq.y), ZV.y);                              \
        }
#define PAIRPK(ACCA, ACCB, W0, W1_, ZV)                                      \
        {                                                                    \
            const f32x2 u0 = {EXP2(ACCA[0]), EXP2(ACCB[0])};                 \
            const f32x2 u1 = {EXP2(ACCA[1]), EXP2(ACCB[1])};                 \
            const f32x2 n01 = FMA2(W0, u1, FMA2(W1_, u0, W0 + W1_));         \
            const f32x2 d01 = FMA2(u0, u1, u0 + u1) + (f32x2){1.0f, 1.0f};   \
            ZV.x = fmaf(n01.x, RCP(d01.x), ZV.x);                            \
            ZV.y = fmaf(n01.y, RCP(d01.y), ZV.y);                            \
        }

    float* outp = out + ((size_t)b * TLEN + t0) * NGF + f0 + jj;
    const int hi = (lane >> 4) & 1;     // lanes 16-31 emit the odd tile

    const float* spbase = &seg[jj * SW + 2 * wave + 8 * q];

    // ---- 5 fully-unrolled 2-tile iterations with 1-ahead LDS prefetch
    f32x2 r0, r1, r2, r3; float p8;
    {
        const f32x2* sp2 = (const f32x2*)spbase;
        r0 = sp2[0]; r1 = sp2[1]; r2 = sp2[2]; r3 = sp2[3];
        p8 = ((const float*)(sp2 + 4))[0];
    }

    #pragma unroll
    for (int i = 0; i < 5; ++i) {
        const int tt0 = 2 * wave + 8 * i;

        const float p0 = r0.x, p1 = r0.y, p2 = r1.x, p3 = r1.y;
        const float p4 = r2.x, p5 = r2.y, p6 = r3.x, p7 = r3.y;
        const float p8c = p8;

        int a0, a1, a2, a3, c0, c1, c2, c3;
        asm("v_cvt_pk_bf16_f32 %0, %1, %2" : "=v"(a0) : "v"(p0), "v"(p1));
        asm("v_cvt_pk_bf16_f32 %0, %1, %2" : "=v"(a1) : "v"(p2), "v"(p3));
        asm("v_cvt_pk_bf16_f32 %0, %1, %2" : "=v"(a2) : "v"(p4), "v"(p5));
        asm("v_cvt_pk_bf16_f32 %0, %1, %2" : "=v"(a3) : "v"(p6), "v"(p7));
        asm("v_cvt_pk_bf16_f32 %0, %1, %2" : "=v"(c0) : "v"(p1), "v"(p2));
        asm("v_cvt_pk_bf16_f32 %0, %1, %2" : "=v"(c1) : "v"(p3), "v"(p4));
        asm("v_cvt_pk_bf16_f32 %0, %1, %2" : "=v"(c2) : "v"(p5), "v"(p6));
        asm("v_cvt_pk_bf16_f32 %0, %1, %2" : "=v"(c3) : "v"(p7), "v"(p8c));

        // prefetch next iteration's window under the MFMA/epilogue
        if (i < 4) {
            const f32x2* spn = (const f32x2*)(spbase + 8 * (i + 1));
            r0 = spn[0]; r1 = spn[1]; r2 = spn[2]; r3 = spn[3];
            p8 = ((const float*)(spn + 4))[0];
        }

        union { int i4[4]; short8 s8; } bfa, bfb;
        bfa.i4[0] = a0; bfa.i4[1] = a1;
        bfa.i4[2] = (a2 & selA) | selB;
        bfa.i4[3] = a3;
        bfb.i4[0] = c0; bfb.i4[1] = c1;
        bfb.i4[2] = (c2 & selA) | selB;
        bfb.i4[3] = c3;

        f32x4 s00 = {0,0,0,0}, s01 = {0,0,0,0}, s02 = {0,0,0,0}, s03 = {0,0,0,0};
        f32x4 s10 = {0,0,0,0}, s11 = {0,0,0,0}, s12 = {0,0,0,0}, s13 = {0,0,0,0};
        s00 = __builtin_amdgcn_mfma_f32_16x16x32_bf16(w1f0.s8, bfa.s8, s00, 0, 0, 0);
        s10 = __builtin_amdgcn_mfma_f32_16x16x32_bf16(w1f0.s8, bfb.s8, s10, 0, 0, 0);
        s01 = __builtin_amdgcn_mfma_f32_16x16x32_bf16(w1f1.s8, bfa.s8, s01, 0, 0, 0);
        s11 = __builtin_amdgcn_mfma_f32_16x16x32_bf16(w1f1.s8, bfb.s8, s11, 0, 0, 0);
        s02 = __builtin_amdgcn_mfma_f32_16x16x32_bf16(w1f2.s8, bfa.s8, s02, 0, 0, 0);
        s12 = __builtin_amdgcn_mfma_f32_16x16x32_bf16(w1f2.s8, bfb.s8, s12, 0, 0, 0);
        s03 = __builtin_amdgcn_mfma_f32_16x16x32_bf16(w1f3.s8, bfa.s8, s03, 0, 0, 0);
        s13 = __builtin_amdgcn_mfma_f32_16x16x32_bf16(w1f3.s8, bfb.s8, s13, 0, 0, 0);

        f32x2 zv = {0.0f, 0.0f};        // .x = tile0, .y = tile1
        QUADPK(s00, s10, wa0, wa1, wa2, wa3, zv)
        QUADPK(s01, s11, wb0, wb1, wb2, wb3, zv)
        QUADPK(s02, s12, wc0, wc1, wc2, wc3, zv)
        PAIRPK(s03, s13, wd0, wd1, zv)

        float z0 = zv.x, z1 = zv.y;
        z0 += __shfl_xor(z0, 16);
        z0 += __shfl_xor(z0, 32);
        z1 += __shfl_xor(z1, 16);
        z1 += __shfl_xor(z1, 32);

        const float o = SIG((hi ? z1 : z0) + nb2);
        if (lane < 32)
            outp[(tt0 + hi) * NGF] = o;
    }
#undef QUADPK
#undef PAIRPK
}

extern "C" void kernel_launch(void* const* d_in, const int* in_sizes, int n_in,
                              void* d_out, int out_size, void* d_ws, size_t ws_size,
                              hipStream_t stream) {
    const float* x  = (const float*)d_in[0];
    const float* W1 = (const float*)d_in[1];
    const float* b1 = (const float*)d_in[2];
    const float* W2 = (const float*)d_in[3];
    const float* b2 = (const float*)d_in[4];
    float* out = (float*)d_out;

    const int B = in_sizes[0] / (NGF * TLEN);  // 32

    dim3 grid((TLEN / TC) * 5, B);             // (125, 32) = 4000 blocks
    relevance_mfma<<<grid, 256, 0, stream>>>(x, W1, b1, W2, b2, out);
}

// Round 14
// 41.641 us; speedup vs baseline: 1.0676x; 1.0676x over previous
//
#include <hip/hip_runtime.h>
#include <cstddef>

constexpr int NGF    = 80;
constexpr int TLEN   = 1000;
constexpr int SPLICE = 10;
constexpr int PATCH  = 2 * SPLICE + 1;  // 21
constexpr int NH     = 50;
constexpr int FB     = 16;              // f per block
constexpr int TC     = 40;              // t per block
constexpr int SW     = 74;              // even (float2 reads); 74%32=10 spreads banks
constexpr float NL2E = -1.44269504088896341f;

typedef __attribute__((ext_vector_type(8))) short  short8;
typedef __attribute__((ext_vector_type(4))) float  f32x4;
typedef __attribute__((ext_vector_type(2))) float  f32x2;

__device__ __forceinline__ unsigned short f32_to_bf16(float f) {
    unsigned int u = __builtin_bit_cast(unsigned int, f);
    u += 0x7fffu + ((u >> 16) & 1u);   // RNE
    return (unsigned short)(u >> 16);
}

#define SIG(s)  __builtin_amdgcn_rcpf(1.0f + __builtin_amdgcn_exp2f(s))
#define EXP2(s) __builtin_amdgcn_exp2f(s)
#define RCP(s)  __builtin_amdgcn_rcpf(s)
#define FMA2(a, b, c) __builtin_elementwise_fma((a), (b), (c))

__global__ __launch_bounds__(256, 4) void relevance_mfma(
    const float* __restrict__ x,    // [B, NGF, TLEN]
    const float* __restrict__ W1,   // [NH, PATCH]
    const float* __restrict__ b1,   // [NH]
    const float* __restrict__ W2,   // [NH]
    const float* __restrict__ b2,   // [1]
    float* __restrict__ out)        // [B, TLEN, NGF]
{
    const int tid  = threadIdx.x;
    const int wave = tid >> 6;
    const int lane = tid & 63;
    const int q    = lane >> 4;
    const int jj   = lane & 15;
    const unsigned bx = blockIdx.x;
    const int fc   = bx % 5u;           // f-chunk
    const int tc   = bx / 5u;           // t-chunk
    const int f0   = fc * FB;
    const int t0   = tc * TC;
    const int b    = blockIdx.y;

    __shared__ float  seg[FB * SW];     // seg[fl][c] = xpad[b][f0+fl][t0+c]
    __shared__ uint4  frg[4][64];       // W1 fragments, built once per block
    __shared__ float4 w2s[4][64];       // per-lane W2 quads, built once per block

    // ---- stage x region (zero-padded)
    const float* xb = x + ((size_t)b * NGF + f0) * TLEN;
    for (int i = tid; i < FB * SW; i += 256) {
        const unsigned fl = (unsigned)i / SW;
        const int c = i - (int)fl * SW;
        const int gx = t0 + c - SPLICE;
        seg[i] = (gx >= 0 && gx < TLEN) ? xb[fl * TLEN + gx] : 0.0f;
    }

    // ---- fragment build, deduplicated: wave n builds fragment-set n only.
    // A = W1 (M = j). A[m=jj][k=8q+e], pre-scaled by -log2(e), b1 in k=21.
    {
        const int j = 16 * wave + jj;
        unsigned int us[8];
        #pragma unroll
        for (int e = 0; e < 8; ++e) {
            const int k = 8 * q + e;
            float v = 0.0f;
            if (j < NH) {
                if (k < PATCH)       v = NL2E * W1[j * PATCH + k];
                else if (k == PATCH) v = NL2E * b1[j];
            }
            us[e] = f32_to_bf16(v);
        }
        uint4 u;
        u.x = us[0] | (us[1] << 16);
        u.y = us[2] | (us[3] << 16);
        u.z = us[4] | (us[5] << 16);
        u.w = us[6] | (us[7] << 16);
        frg[wave][lane] = u;

        const int jw = 16 * wave + 4 * q;   // this lane's W2 quad for set `wave`
        float4 wv;
        wv.x = (jw + 0 < NH) ? NL2E * W2[jw + 0] : 0.0f;
        wv.y = (jw + 1 < NH) ? NL2E * W2[jw + 1] : 0.0f;
        wv.z = (jw + 2 < NH) ? NL2E * W2[jw + 2] : 0.0f;
        wv.w = (jw + 3 < NH) ? NL2E * W2[jw + 3] : 0.0f;
        w2s[wave][lane] = wv;
    }

    __syncthreads();

    // ---- every wave reads the shared fragments back
    union FragU { uint4 u4; short8 s8; };
    FragU w1f0, w1f1, w1f2, w1f3;
    w1f0.u4 = frg[0][lane];
    w1f1.u4 = frg[1][lane];
    w1f2.u4 = frg[2][lane];
    w1f3.u4 = frg[3][lane];

    float w2v[16];
    {
        const float4 t0v = w2s[0][lane], t1v = w2s[1][lane];
        const float4 t2v = w2s[2][lane], t3v = w2s[3][lane];
        w2v[0]=t0v.x;  w2v[1]=t0v.y;  w2v[2]=t0v.z;  w2v[3]=t0v.w;
        w2v[4]=t1v.x;  w2v[5]=t1v.y;  w2v[6]=t1v.z;  w2v[7]=t1v.w;
        w2v[8]=t2v.x;  w2v[9]=t2v.y;  w2v[10]=t2v.z; w2v[11]=t2v.w;
        w2v[12]=t3v.x; w2v[13]=t3v.y; w2v[14]=t3v.z; w2v[15]=t3v.w;
    }
    // packed W2 for the (s0,s1) dual-quad: element .x -> s0 quad, .y -> s1 quad
    const f32x2 wp0 = {w2v[0], w2v[4]};
    const f32x2 wp1 = {w2v[1], w2v[5]};
    const f32x2 wp2 = {w2v[2], w2v[6]};
    const f32x2 wp3 = {w2v[3], w2v[7]};
    const float nb2 = NL2E * b2[0];

    // bias-slot patch masks (k=21 lives in q==2's dword 2 hi half)
    const int selA = (q == 2) ? 0x0000FFFF : ~0;
    const int selB = (q == 2) ? 0x3F800000 : 0;

    // dual quad-rational on (ACCA, ACCB) packed into f32x2 lanes
#define QUADPK(ACCA, ACCB, Z)                                                \
        {                                                                    \
            const f32x2 u0 = {EXP2(ACCA[0]), EXP2(ACCB[0])};                 \
            const f32x2 u1 = {EXP2(ACCA[1]), EXP2(ACCB[1])};                 \
            const f32x2 u2 = {EXP2(ACCA[2]), EXP2(ACCB[2])};                 \
            const f32x2 u3 = {EXP2(ACCA[3]), EXP2(ACCB[3])};                 \
            const f32x2 n01 = FMA2(wp0, u1, FMA2(wp1, u0, wp0 + wp1));       \
            const f32x2 n23 = FMA2(wp2, u3, FMA2(wp3, u2, wp2 + wp3));       \
            const f32x2 d01 = FMA2(u0, u1, u0 + u1) + (f32x2){1.0f, 1.0f};   \
            const f32x2 d23 = FMA2(u2, u3, u2 + u3) + (f32x2){1.0f, 1.0f};   \
            const f32x2 nq  = FMA2(n01, d23, n23 * d01);                     \
            const f32x2 dq  = d01 * d23;                                     \
            Z = fmaf(nq.x, RCP(dq.x), Z);                                    \
            Z = fmaf(nq.y, RCP(dq.y), Z);                                    \
        }
#define QUAD(ACC, N, Z)                                                      \
        {                                                                    \
            const float w0 = w2v[4*N+0], w1 = w2v[4*N+1];                    \
            const float w2_ = w2v[4*N+2], w3 = w2v[4*N+3];                   \
            const float u0 = EXP2(ACC[0]);                                   \
            const float u1 = EXP2(ACC[1]);                                   \
            const float u2 = EXP2(ACC[2]);                                   \
            const float u3 = EXP2(ACC[3]);                                   \
            const float n01 = fmaf(w0, u1, fmaf(w1, u0, w0 + w1));           \
            const float n23 = fmaf(w2_, u3, fmaf(w3, u2, w2_ + w3));         \
            const float d01 = fmaf(u0, u1, u0 + u1) + 1.0f;                  \
            const float d23 = fmaf(u2, u3, u2 + u3) + 1.0f;                  \
            const float nq  = fmaf(n01, d23, n23 * d01);                     \
            const float dq  = d01 * d23;                                     \
            Z = fmaf(nq, RCP(dq), Z);                                        \
        }
#define PAIR(ACC, Z)                                                         \
        {                                                                    \
            const float w0 = w2v[12], w1 = w2v[13];                          \
            const float u0 = EXP2(ACC[0]);                                   \
            const float u1 = EXP2(ACC[1]);                                   \
            const float n01 = fmaf(w0, u1, fmaf(w1, u0, w0 + w1));           \
            const float d01 = fmaf(u0, u1, u0 + u1) + 1.0f;                  \
            Z = fmaf(n01, RCP(d01), Z);                                      \
        }

    float* outp = out + ((size_t)b * TLEN + t0) * NGF + f0 + jj;
    const int hi = (lane >> 4) & 1;     // lanes 16-31 emit the odd tile

    // ---- 2-tile iterations: tt0 = 2*wave + 8*i (even), tt1 = tt0+1;
    // windows share 7/8 floats -> 5 LDS reads + 8 cvts for both tiles.
    for (int i = 0; i < 5; ++i) {
        const int tt0 = 2 * wave + 8 * i;

        const f32x2* sp2 = (const f32x2*)&seg[jj * SW + tt0 + 8 * q];
        const f32x2 r0 = sp2[0], r1 = sp2[1], r2 = sp2[2], r3 = sp2[3];
        const float p8 = ((const float*)(sp2 + 4))[0];
        const float p0 = r0.x, p1 = r0.y, p2 = r1.x, p3 = r1.y;
        const float p4 = r2.x, p5 = r2.y, p6 = r3.x, p7 = r3.y;

        int a0, a1, a2, a3, c0, c1, c2, c3;
        asm("v_cvt_pk_bf16_f32 %0, %1, %2" : "=v"(a0) : "v"(p0), "v"(p1));
        asm("v_cvt_pk_bf16_f32 %0, %1, %2" : "=v"(a1) : "v"(p2), "v"(p3));
        asm("v_cvt_pk_bf16_f32 %0, %1, %2" : "=v"(a2) : "v"(p4), "v"(p5));
        asm("v_cvt_pk_bf16_f32 %0, %1, %2" : "=v"(a3) : "v"(p6), "v"(p7));
        asm("v_cvt_pk_bf16_f32 %0, %1, %2" : "=v"(c0) : "v"(p1), "v"(p2));
        asm("v_cvt_pk_bf16_f32 %0, %1, %2" : "=v"(c1) : "v"(p3), "v"(p4));
        asm("v_cvt_pk_bf16_f32 %0, %1, %2" : "=v"(c2) : "v"(p5), "v"(p6));
        asm("v_cvt_pk_bf16_f32 %0, %1, %2" : "=v"(c3) : "v"(p7), "v"(p8));

        union { int i4[4]; short8 s8; } bfa, bfb;
        bfa.i4[0] = a0; bfa.i4[1] = a1;
        bfa.i4[2] = (a2 & selA) | selB;
        bfa.i4[3] = a3;
        bfb.i4[0] = c0; bfb.i4[1] = c1;
        bfb.i4[2] = (c2 & selA) | selB;
        bfb.i4[3] = c3;

        f32x4 s00 = {0,0,0,0}, s01 = {0,0,0,0}, s02 = {0,0,0,0}, s03 = {0,0,0,0};
        f32x4 s10 = {0,0,0,0}, s11 = {0,0,0,0}, s12 = {0,0,0,0}, s13 = {0,0,0,0};
        s00 = __builtin_amdgcn_mfma_f32_16x16x32_bf16(w1f0.s8, bfa.s8, s00, 0, 0, 0);
        s10 = __builtin_amdgcn_mfma_f32_16x16x32_bf16(w1f0.s8, bfb.s8, s10, 0, 0, 0);
        s01 = __builtin_amdgcn_mfma_f32_16x16x32_bf16(w1f1.s8, bfa.s8, s01, 0, 0, 0);
        s11 = __builtin_amdgcn_mfma_f32_16x16x32_bf16(w1f1.s8, bfb.s8, s11, 0, 0, 0);
        s02 = __builtin_amdgcn_mfma_f32_16x16x32_bf16(w1f2.s8, bfa.s8, s02, 0, 0, 0);
        s12 = __builtin_amdgcn_mfma_f32_16x16x32_bf16(w1f2.s8, bfb.s8, s12, 0, 0, 0);
        s03 = __builtin_amdgcn_mfma_f32_16x16x32_bf16(w1f3.s8, bfa.s8, s03, 0, 0, 0);
        s13 = __builtin_amdgcn_mfma_f32_16x16x32_bf16(w1f3.s8, bfb.s8, s13, 0, 0, 0);

        float z0 = 0.0f, z1 = 0.0f;
        QUADPK(s00, s01, z0) QUADPK(s10, s11, z1)
        QUAD(s02, 2, z0)     QUAD(s12, 2, z1)
        PAIR(s03, z0)        PAIR(s13, z1)

        z0 += __shfl_xor(z0, 16);
        z0 += __shfl_xor(z0, 32);
        z1 += __shfl_xor(z1, 16);
        z1 += __shfl_xor(z1, 32);

        // lanes 0-15 emit tile0, 16-31 tile1: ONE sigmoid + ONE store per pair
        const float o = SIG((hi ? z1 : z0) + nb2);
        if (lane < 32)
            outp[(tt0 + hi) * NGF] = o;
    }
#undef QUADPK
#undef QUAD
#undef PAIR
}

extern "C" void kernel_launch(void* const* d_in, const int* in_sizes, int n_in,
                              void* d_out, int out_size, void* d_ws, size_t ws_size,
                              hipStream_t stream) {
    const float* x  = (const float*)d_in[0];
    const float* W1 = (const float*)d_in[1];
    const float* b1 = (const float*)d_in[2];
    const float* W2 = (const float*)d_in[3];
    const float* b2 = (const float*)d_in[4];
    float* out = (float*)d_out;

    const int B = in_sizes[0] / (NGF * TLEN);  // 32

    dim3 grid((TLEN / TC) * 5, B);             // (125, 32) = 4000 blocks
    relevance_mfma<<<grid, 256, 0, stream>>>(x, W1, b1, W2, b2, out);
}